// Round 8
// baseline (58.086 us; speedup 1.0000x reference)
//
#include <hip/hip_runtime.h>
#include <cstddef>
#include <cstdint>

// Problem constants
#define Bb   32
#define Ss   512
#define Dd   768
#define Ww   256
#define Pp   1024
#define NH   300          // hidden
#define SLOT1 320         // slot-1 column base (128B-aligned: 320*2B = 640B)
#define NPAD 640          // padded proj row: [0,300) slot0, [320,620) slot1
#define Mm   (Bb * Ww)    // 8192 words
#define ZOFF (Mm * NPAD)  // zero-row offset inside proj (row 8192)

typedef __attribute__((ext_vector_type(8))) short bf16x8;
typedef __attribute__((ext_vector_type(4))) float f32x4;

#define GPTR(p) ((const __attribute__((address_space(1))) void*)(p))
#define LPTR(p) ((__attribute__((address_space(3))) void*)(p))

__device__ __forceinline__ unsigned short f2bf(float x) {
    unsigned u = __builtin_bit_cast(unsigned, x);
    u += 0x7fffu + ((u >> 16) & 1u);          // RNE
    return (unsigned short)(u >> 16);
}
__device__ __forceinline__ float bf2f(unsigned short u) {
    return __builtin_bit_cast(float, (unsigned)u << 16);
}
__device__ __forceinline__ float fast_tanh(float x) {
    x = fminf(fmaxf(x, -15.0f), 15.0f);
    float e = __expf(2.0f * x);
    return 1.0f - 2.0f * __builtin_amdgcn_rcpf(e + 1.0f);
}

// -------------------------------------------------------------------------
// Kernel 1 (prep): blocks [0, 8192): mean-pool h -> emb bf16 (one word/block)
//                  blocks [8192, 8192+2560): repack w1 -> BmatT bf16
//                  block  8192+2560: zero proj row 8192 (dummy gather row)
//   BmatT[n][k] = n<300 ? w1[k][n] : (320<=n<620 ? w1[768+k][n-320] : 0)
// -------------------------------------------------------------------------
__global__ __launch_bounds__(192) void prep_kernel(
    const float* __restrict__ h, const float* __restrict__ w1,
    const int* __restrict__ word_start, const int* __restrict__ word_len,
    unsigned short* __restrict__ emb, unsigned short* __restrict__ bmatT,
    unsigned short* __restrict__ proj)
{
    const int bid = blockIdx.x;
    const int t   = threadIdx.x;      // 0..191
    if (bid < Mm) {
        const int m   = bid;
        const int b   = m >> 8;
        const int s0  = word_start[m];
        const int len = word_len[m];
        const float* p = h + (size_t)b * (Ss * Dd) + (size_t)s0 * Dd + t * 4;
        float4 v = *(const float4*)p;
        if (len == 2) {
            float4 v2 = *(const float4*)(p + Dd);
            v.x = (v.x + v2.x) * 0.5f;
            v.y = (v.y + v2.y) * 0.5f;
            v.z = (v.z + v2.z) * 0.5f;
            v.w = (v.w + v2.w) * 0.5f;
        }
        ushort4 o = make_ushort4(f2bf(v.x), f2bf(v.y), f2bf(v.z), f2bf(v.w));
        *(ushort4*)(emb + (size_t)m * Dd + t * 4) = o;
    } else if (bid < Mm + 4 * NPAD) {
        const int rb = bid - Mm;
        const int n  = rb >> 2;                 // 0..639
        const int k  = ((rb & 3) * 192) + t;    // 0..767
        float v = 0.0f;
        if (n < NH)                            v = w1[(size_t)k * NH + n];
        else if (n >= SLOT1 && n < SLOT1 + NH) v = w1[(size_t)(Dd + k) * NH + (n - SLOT1)];
        bmatT[(size_t)n * Dd + k] = f2bf(v);
    } else {
        if (t < NPAD / 4)
            *(ushort4*)(proj + ZOFF + t * 4) = make_ushort4(0, 0, 0, 0);
    }
}

// -------------------------------------------------------------------------
// Kernel 2: MFMA bf16 GEMM: proj[8192][640] = emb[8192][768] @ Bmat[768][640]
// Tile 64x128 -> 640 blocks (2.5/CU, tail-balanced). BK=32, 4 waves (2x2),
// each wave 32x64 (2x4 frags). Double-buffered LDS, 1 barrier per K-step.
// Bijective XCD swizzle (640 = 8*80); 5 consecutive swz share an A-band.
// -------------------------------------------------------------------------
__global__ __launch_bounds__(256) void gemm_kernel(
    const unsigned short* __restrict__ emb, const unsigned short* __restrict__ bmatT,
    unsigned short* __restrict__ proj)
{
    __shared__ bf16x8 Al[2][4][64];    // 8 KB  (per buf 4096 B)
    __shared__ bf16x8 Bl[2][4][128];   // 16 KB (per buf 8192 B)

    const int bid = blockIdx.x;
    const int t   = threadIdx.x;

    const int swz   = (bid & 7) * 80 + (bid >> 3);
    const int mBase = (swz / 5) * 64;
    const int nBase = (swz % 5) * 128;

    // staging: A unit t = (row t&63, oct t>>6), dest byte t*16 (linear)
    //          B units t, t+256 = (col t&127, oct t>>7 / +2), dest t*16, +4096
    const unsigned short* srcA = emb   + (size_t)(mBase + (t & 63))  * Dd + ((t >> 6) << 3);
    const unsigned short* srcB = bmatT + (size_t)(nBase + (t & 127)) * Dd + ((t >> 7) << 3);
    char* ldsA = (char*)&Al[0][0][0] + t * 16;
    char* ldsB = (char*)&Bl[0][0][0] + t * 16;

    const int lane = t & 63;
    const int w    = t >> 6;
    const int wr   = w >> 1;        // row half (32 rows)
    const int wc   = w & 1;         // col half (64 cols)
    const int fr   = lane & 15;
    const int kb   = lane >> 4;

    f32x4 acc[2][4];
#pragma unroll
    for (int i = 0; i < 2; ++i)
#pragma unroll
        for (int j = 0; j < 4; ++j)
#pragma unroll
            for (int r = 0; r < 4; ++r) acc[i][j][r] = 0.0f;

#define STAGE(c, off)                                                                          \
    __builtin_amdgcn_global_load_lds(GPTR(srcA + (off)),      LPTR(ldsA + (c) * 4096),        16, 0, 0); \
    __builtin_amdgcn_global_load_lds(GPTR(srcB + (off)),      LPTR(ldsB + (c) * 8192),        16, 0, 0); \
    __builtin_amdgcn_global_load_lds(GPTR(srcB + (off) + 16), LPTR(ldsB + (c) * 8192 + 4096), 16, 0, 0)

#define COMPUTE(c)                                                                             \
    {                                                                                          \
        bf16x8 a[2], b[4];                                                                     \
        _Pragma("unroll")                                                                      \
        for (int mi = 0; mi < 2; ++mi) a[mi] = Al[c][kb][wr * 32 + mi * 16 + fr];              \
        _Pragma("unroll")                                                                      \
        for (int ni = 0; ni < 4; ++ni) b[ni] = Bl[c][kb][wc * 64 + ni * 16 + fr];              \
        _Pragma("unroll")                                                                      \
        for (int mi = 0; mi < 2; ++mi)                                                         \
            _Pragma("unroll")                                                                  \
            for (int ni = 0; ni < 4; ++ni)                                                     \
                acc[mi][ni] = __builtin_amdgcn_mfma_f32_16x16x32_bf16(a[mi], b[ni], acc[mi][ni], 0, 0, 0); \
    }

    STAGE(0, 0);
    __syncthreads();                 // vmcnt(0) drain + barrier: buf0 ready
    int cur = 0;
    for (int k0 = 32; k0 < Dd; k0 += 32) {
        STAGE(cur ^ 1, k0);          // next-tile loads fly under compute
        COMPUTE(cur);
        __syncthreads();
        cur ^= 1;
    }
    COMPUTE(cur);
#undef STAGE
#undef COMPUTE

    // C/D layout: col = lane&15, row = (lane>>4)*4 + r   [verified m89/m91]
    const int r0 = mBase + wr * 32 + kb * 4;
    const int c0 = nBase + wc * 64 + fr;
#pragma unroll
    for (int mi = 0; mi < 2; ++mi)
#pragma unroll
        for (int ni = 0; ni < 4; ++ni)
#pragma unroll
            for (int r = 0; r < 4; ++r)
                proj[(size_t)(r0 + mi * 16 + r) * NPAD + c0 + ni * 16] = f2bf(acc[mi][ni][r]);
}

// -------------------------------------------------------------------------
// Kernel 3: per-pair tanh + 300x4 matvec + softmax. 8 PAIRS PER WAVE:
// all 80 gathers unconditional (invalid slot -> proj zero row 8192),
// softmax finished on lanes 0..7.
// -------------------------------------------------------------------------
__global__ __launch_bounds__(256) void mlp_kernel(
    const unsigned short* __restrict__ proj,
    const float* __restrict__ b1, const float* __restrict__ w2,
    const float* __restrict__ b2, const int* __restrict__ pair_idx,
    float* __restrict__ out)
{
    const int wave = blockIdx.x * 4 + (threadIdx.x >> 6);   // 0..4095
    const int lane = threadIdx.x & 63;
    const int wid0 = wave * 8;                              // 8 pairs, same batch
    const int b    = wid0 >> 10;
    const int wbase = b * Ww;

    int idx[16];
#pragma unroll
    for (int q = 0; q < 4; ++q) {
        const int4 pi = *(const int4*)(pair_idx + wid0 * 2 + q * 4);
        idx[q * 4 + 0] = pi.x; idx[q * 4 + 1] = pi.y;
        idx[q * 4 + 2] = pi.z; idx[q * 4 + 3] = pi.w;
    }

    // int offsets: invalid slot -> zero row
    int off0[8], off1[8];
#pragma unroll
    for (int p = 0; p < 8; ++p) {
        const int i0 = idx[p * 2], i1 = idx[p * 2 + 1];
        off0[p] = (i0 >= 0) ? (wbase + i0) * NPAD : ZOFF;
        off1[p] = ((i1 >= 0) ? (wbase + i1) * NPAD : ZOFF) + SLOT1;
    }

    // issue all 80 gathers up front (one deep independent clause)
    unsigned short g0[8][5], g1[8][5];
#pragma unroll
    for (int p = 0; p < 8; ++p)
#pragma unroll
        for (int it = 0; it < 5; ++it) {
            const int j = lane + it * 64;     // j<320; cols [300,320) are zero
            g0[p][it] = proj[(size_t)off0[p] + j];
            g1[p][it] = proj[(size_t)off1[p] + j];
        }

    float acc[8][4];
#pragma unroll
    for (int p = 0; p < 8; ++p)
#pragma unroll
        for (int c = 0; c < 4; ++c) acc[p][c] = 0.0f;

#pragma unroll
    for (int it = 0; it < 5; ++it) {
        const int j  = lane + it * 64;
        const bool ok = (j < NH);             // divergent only at it=4
        const float bj = ok ? b1[j] : 0.0f;
        float4 wv = make_float4(0.f, 0.f, 0.f, 0.f);
        if (ok) wv = *(const float4*)(w2 + (size_t)j * 4);
#pragma unroll
        for (int p = 0; p < 8; ++p) {
            const float v = bj + bf2f(g0[p][it]) + bf2f(g1[p][it]);
            const float x = ok ? fast_tanh(v) : 0.0f;
            acc[p][0] = fmaf(x, wv.x, acc[p][0]);
            acc[p][1] = fmaf(x, wv.y, acc[p][1]);
            acc[p][2] = fmaf(x, wv.z, acc[p][2]);
            acc[p][3] = fmaf(x, wv.w, acc[p][3]);
        }
    }

    // butterfly reduce: afterwards every lane holds all 32 sums
#pragma unroll
    for (int off = 32; off >= 1; off >>= 1)
#pragma unroll
        for (int p = 0; p < 8; ++p)
#pragma unroll
            for (int c = 0; c < 4; ++c)
                acc[p][c] += __shfl_xor(acc[p][c], off, 64);

    // lane p (p<8) finishes pair p's softmax (static register indexing)
    float l0 = 0.f, l1 = 0.f, l2 = 0.f, l3 = 0.f;
#pragma unroll
    for (int p = 0; p < 8; ++p)
        if (lane == p) { l0 = acc[p][0]; l1 = acc[p][1]; l2 = acc[p][2]; l3 = acc[p][3]; }

    if (lane < 8) {
        l0 += b2[0]; l1 += b2[1]; l2 += b2[2]; l3 += b2[3];
        const float mx = fmaxf(fmaxf(l0, l1), fmaxf(l2, l3));
        const float e0 = __expf(l0 - mx), e1 = __expf(l1 - mx);
        const float e2 = __expf(l2 - mx), e3 = __expf(l3 - mx);
        const float inv = 1.0f / (e0 + e1 + e2 + e3);
        float4 o = {e0 * inv, e1 * inv, e2 * inv, e3 * inv};
        *(float4*)(out + (size_t)(wid0 + lane) * 4) = o;
    }
}

// -------------------------------------------------------------------------
extern "C" void kernel_launch(void* const* d_in, const int* in_sizes, int n_in,
                              void* d_out, int out_size, void* d_ws, size_t ws_size,
                              hipStream_t stream)
{
    const float* h          = (const float*)d_in[0];
    const float* w1         = (const float*)d_in[1];
    const float* b1         = (const float*)d_in[2];
    const float* w2         = (const float*)d_in[3];
    const float* b2         = (const float*)d_in[4];
    const int*   word_start = (const int*)d_in[5];
    const int*   word_len   = (const int*)d_in[6];
    const int*   pair_idx   = (const int*)d_in[7];
    float*       out        = (float*)d_out;

    // workspace layout (all bf16)
    unsigned short* proj  = (unsigned short*)d_ws;                       // 8193 rows x 640 = 10,487,040 B
    unsigned short* emb   = (unsigned short*)((char*)d_ws + 16777216);   // 12,582,912 B
    unsigned short* bmatT = (unsigned short*)((char*)d_ws + 31457280);   // 983,040 B

    prep_kernel<<<dim3(Mm + 4 * NPAD + 1), dim3(192), 0, stream>>>(
        h, w1, word_start, word_len, emb, bmatT, proj);
    gemm_kernel<<<dim3(640), dim3(256), 0, stream>>>(emb, bmatT, proj);
    mlp_kernel <<<dim3(1024), dim3(256), 0, stream>>>(proj, b1, w2, b2, pair_idx, out);
}

// Round 9
// 52.165 us; speedup vs baseline: 1.1135x; 1.1135x over previous
//
#include <hip/hip_runtime.h>
#include <cstddef>
#include <cstdint>

// Problem constants
#define Bb   32
#define Ss   512
#define Dd   768
#define Ww   256
#define Pp   1024
#define NH   300          // hidden
#define SLOT1 320         // slot-1 column base (128B-aligned)
#define NPAD 640          // padded proj row: [0,300) slot0, [320,620) slot1
#define Mm   (Bb * Ww)    // 8192 words

typedef __attribute__((ext_vector_type(8))) short bf16x8;
typedef __attribute__((ext_vector_type(4))) float f32x4;

#define GPTR(p) ((const __attribute__((address_space(1))) void*)(p))
#define LPTR(p) ((__attribute__((address_space(3))) void*)(p))

__device__ __forceinline__ unsigned short f2bf(float x) {
    unsigned u = __builtin_bit_cast(unsigned, x);
    u += 0x7fffu + ((u >> 16) & 1u);          // RNE
    return (unsigned short)(u >> 16);
}
__device__ __forceinline__ float bf2f(unsigned short u) {
    return __builtin_bit_cast(float, (unsigned)u << 16);
}
__device__ __forceinline__ float fast_tanh(float x) {
    x = fminf(fmaxf(x, -15.0f), 15.0f);
    float e = __expf(2.0f * x);
    return 1.0f - 2.0f * __builtin_amdgcn_rcpf(e + 1.0f);
}

// -------------------------------------------------------------------------
// Kernel 1 (prep), grid-stride 1024x256:
//   (a) mean-pool h -> emb bf16          (Mm*192 float4 units)
//   (b) repack w1 -> BmatT bf16          (Dd*NPAD units)
//       BmatT[n][k] = n<300 ? w1[k][n] : (320<=n<620 ? w1[768+k][n-320] : 0)
//   (c) zero dummy gather row zrow
// -------------------------------------------------------------------------
__global__ __launch_bounds__(256) void prep_kernel(
    const float* __restrict__ h, const float* __restrict__ w1,
    const int* __restrict__ word_start, const int* __restrict__ word_len,
    unsigned short* __restrict__ emb, unsigned short* __restrict__ bmatT,
    unsigned short* __restrict__ zrow)
{
    const int gid    = blockIdx.x * 256 + threadIdx.x;
    const int stride = 1024 * 256;

    // (a) pool: unit u = word m, float4-chunk c
    for (int u = gid; u < Mm * 192; u += stride) {
        const int m = u / 192;
        const int c = u - m * 192;
        const int b   = m >> 8;
        const int s0  = word_start[m];
        const int len = word_len[m];
        const float* p = h + (size_t)b * (Ss * Dd) + (size_t)s0 * Dd + c * 4;
        float4 v = *(const float4*)p;
        if (len == 2) {
            float4 v2 = *(const float4*)(p + Dd);
            v.x = (v.x + v2.x) * 0.5f;
            v.y = (v.y + v2.y) * 0.5f;
            v.z = (v.z + v2.z) * 0.5f;
            v.w = (v.w + v2.w) * 0.5f;
        }
        ushort4 o = make_ushort4(f2bf(v.x), f2bf(v.y), f2bf(v.z), f2bf(v.w));
        *(ushort4*)(emb + (size_t)m * Dd + c * 4) = o;
    }

    // (b) repack: unit u = k*NPAD + n  (lane-consecutive n -> coalesced w1 reads)
    for (int u = gid; u < Dd * NPAD; u += stride) {
        const int k = u / NPAD;
        const int n = u - k * NPAD;
        float v = 0.0f;
        if (n < NH)                            v = w1[(size_t)k * NH + n];
        else if (n >= SLOT1 && n < SLOT1 + NH) v = w1[(size_t)(Dd + k) * NH + (n - SLOT1)];
        bmatT[(size_t)n * Dd + k] = f2bf(v);
    }

    // (c) zero row
    if (gid < NPAD / 4)
        *(ushort4*)(zrow + gid * 4) = make_ushort4(0, 0, 0, 0);
}

// -------------------------------------------------------------------------
// Kernel 2: MFMA bf16 GEMM (EXACT R7 winner): proj = emb @ Bmat.
// Tile 128x128, BK=32, 4 waves (2x2), wave 64x64 (4x4 frags).
// 2-phase double-buffered LDS; bijective XCD swizzle (320 = 8*40).
// -------------------------------------------------------------------------
__global__ __launch_bounds__(256) void gemm_kernel(
    const unsigned short* __restrict__ emb, const unsigned short* __restrict__ bmatT,
    unsigned short* __restrict__ proj)
{
    __shared__ bf16x8 Al[2][4][128];   // 16 KB
    __shared__ bf16x8 Bl[2][4][128];   // 16 KB

    const int bid = blockIdx.x;
    const int t   = threadIdx.x;

    const int swz   = (bid & 7) * 40 + (bid >> 3);
    const int mBase = (swz / 5) * 128;
    const int nBase = (swz % 5) * 128;

    const int srow = t & 127;
    const int skb  = t >> 7;
    const unsigned short* srcA = emb   + (size_t)(mBase + srow) * Dd + (skb << 3);
    const unsigned short* srcB = bmatT + (size_t)(nBase + srow) * Dd + (skb << 3);
    char* ldsA = (char*)&Al[0][0][0] + t * 16;
    char* ldsB = (char*)&Bl[0][0][0] + t * 16;

    const int lane = t & 63;
    const int w    = t >> 6;
    const int wr   = w >> 1;
    const int wc   = w & 1;
    const int fr   = lane & 15;
    const int kb   = lane >> 4;

    f32x4 acc[4][4];
#pragma unroll
    for (int i = 0; i < 4; ++i)
#pragma unroll
        for (int j = 0; j < 4; ++j)
#pragma unroll
            for (int r = 0; r < 4; ++r) acc[i][j][r] = 0.0f;

#define STAGE(c, off)                                                                          \
    __builtin_amdgcn_global_load_lds(GPTR(srcA + (off)),      LPTR(ldsA + (c) * 8192),        16, 0, 0); \
    __builtin_amdgcn_global_load_lds(GPTR(srcA + (off) + 16), LPTR(ldsA + (c) * 8192 + 4096), 16, 0, 0); \
    __builtin_amdgcn_global_load_lds(GPTR(srcB + (off)),      LPTR(ldsB + (c) * 8192),        16, 0, 0); \
    __builtin_amdgcn_global_load_lds(GPTR(srcB + (off) + 16), LPTR(ldsB + (c) * 8192 + 4096), 16, 0, 0)

#define COMPUTE(c)                                                                             \
    {                                                                                          \
        bf16x8 a[4], b[4];                                                                     \
        _Pragma("unroll")                                                                      \
        for (int mi = 0; mi < 4; ++mi) a[mi] = Al[c][kb][wr * 64 + mi * 16 + fr];              \
        _Pragma("unroll")                                                                      \
        for (int ni = 0; ni < 4; ++ni) b[ni] = Bl[c][kb][wc * 64 + ni * 16 + fr];              \
        _Pragma("unroll")                                                                      \
        for (int mi = 0; mi < 4; ++mi)                                                         \
            _Pragma("unroll")                                                                  \
            for (int ni = 0; ni < 4; ++ni)                                                     \
                acc[mi][ni] = __builtin_amdgcn_mfma_f32_16x16x32_bf16(a[mi], b[ni], acc[mi][ni], 0, 0, 0); \
    }

    STAGE(0, 0);
    __syncthreads();
    int cur = 0;
    for (int k0 = 32; k0 < Dd; k0 += 32) {
        STAGE(cur ^ 1, k0);
        COMPUTE(cur);
        __syncthreads();
        cur ^= 1;
    }
    COMPUTE(cur);
#undef STAGE
#undef COMPUTE

    const int r0 = mBase + wr * 64 + kb * 4;
    const int c0 = nBase + wc * 64 + fr;
#pragma unroll
    for (int mi = 0; mi < 4; ++mi)
#pragma unroll
        for (int ni = 0; ni < 4; ++ni)
#pragma unroll
            for (int r = 0; r < 4; ++r)
                proj[(size_t)(r0 + mi * 16 + r) * NPAD + c0 + ni * 16] = f2bf(acc[mi][ni][r]);
}

// -------------------------------------------------------------------------
// Kernel 3: 4 pairs per wave (R7 gather structure) + LDS-tree reduce +
// wave-parallel softmax (replaces 96-bpermute butterfly + serial lane<4).
// -------------------------------------------------------------------------
__global__ __launch_bounds__(256) void mlp_kernel(
    const unsigned short* __restrict__ proj, const unsigned short* __restrict__ zrow,
    const float* __restrict__ b1, const float* __restrict__ w2,
    const float* __restrict__ b2, const int* __restrict__ pair_idx,
    float* __restrict__ out)
{
    __shared__ float red[4][64][17];   // [wave][src lane][16 outputs + pad]

    const int wv   = threadIdx.x >> 6;                      // wave in block
    const int wave = blockIdx.x * 4 + wv;                   // 0..8191
    const int lane = threadIdx.x & 63;
    const int wid0 = wave * 4;                              // 4 pairs, same batch
    const int b    = wid0 >> 10;
    const unsigned short* base = proj + (size_t)b * (Ww * NPAD);

    const int4 piA = *(const int4*)(pair_idx + wid0 * 2);
    const int4 piB = *(const int4*)(pair_idx + wid0 * 2 + 4);
    const int idx[8] = {piA.x, piA.y, piA.z, piA.w, piB.x, piB.y, piB.z, piB.w};

    const unsigned short* r0p[4];
    const unsigned short* r1p[4];
#pragma unroll
    for (int p = 0; p < 4; ++p) {
        const int i0 = idx[p * 2], i1 = idx[p * 2 + 1];
        r0p[p] = (i0 >= 0) ? base + (size_t)i0 * NPAD : zrow;
        r1p[p] = ((i1 >= 0) ? base + (size_t)i1 * NPAD : zrow) + SLOT1;
    }

    // issue all 40 gathers up front (coalesced 128B per instr)
    unsigned short g0[4][5], g1[4][5];
#pragma unroll
    for (int p = 0; p < 4; ++p)
#pragma unroll
        for (int it = 0; it < 5; ++it) {
            const int j = lane + it * 64;     // j<320; cols [300,320) are zero
            g0[p][it] = r0p[p][j];
            g1[p][it] = r1p[p][j];
        }

    float acc[4][4];
#pragma unroll
    for (int p = 0; p < 4; ++p)
#pragma unroll
        for (int c = 0; c < 4; ++c) acc[p][c] = 0.0f;

#pragma unroll
    for (int it = 0; it < 5; ++it) {
        const int j  = lane + it * 64;
        const bool ok = (j < NH);             // divergent only at it=4
        const float bj = ok ? b1[j] : 0.0f;
        float4 wv4 = make_float4(0.f, 0.f, 0.f, 0.f);
        if (ok) wv4 = *(const float4*)(w2 + (size_t)j * 4);
#pragma unroll
        for (int p = 0; p < 4; ++p) {
            const float v = bj + bf2f(g0[p][it]) + bf2f(g1[p][it]);
            const float x = ok ? fast_tanh(v) : 0.0f;
            acc[p][0] = fmaf(x, wv4.x, acc[p][0]);
            acc[p][1] = fmaf(x, wv4.y, acc[p][1]);
            acc[p][2] = fmaf(x, wv4.z, acc[p][2]);
            acc[p][3] = fmaf(x, wv4.w, acc[p][3]);
        }
    }

    // LDS tree reduce: lane -> 16 partials, then lane (o,g) sums 16 sources
#pragma unroll
    for (int p = 0; p < 4; ++p)
#pragma unroll
        for (int c = 0; c < 4; ++c)
            red[wv][lane][p * 4 + c] = acc[p][c];
    __syncthreads();

    const int o = lane >> 2;          // output id = p*4+c
    const int g = lane & 3;           // source quarter
    float v = 0.0f;
#pragma unroll
    for (int i = 0; i < 16; ++i)
        v += red[wv][g * 16 + i][o];
    v += __shfl_xor(v, 1, 64);
    v += __shfl_xor(v, 2, 64);        // every lane: full sum for its o

    // wave-parallel softmax across c (lane bits: p=[5:4], c=[3:2], g=[1:0])
    const int c = o & 3;
    const float l = v + b2[c];
    float mx = fmaxf(l, __shfl_xor(l, 4, 64));
    mx = fmaxf(mx, __shfl_xor(mx, 8, 64));
    const float e = __expf(l - mx);
    float s = e + __shfl_xor(e, 4, 64);
    s += __shfl_xor(s, 8, 64);
    const float r = e * __builtin_amdgcn_rcpf(s);
    if (g == 0)
        out[(size_t)(wid0 + (o >> 2)) * 4 + c] = r;
}

// -------------------------------------------------------------------------
extern "C" void kernel_launch(void* const* d_in, const int* in_sizes, int n_in,
                              void* d_out, int out_size, void* d_ws, size_t ws_size,
                              hipStream_t stream)
{
    const float* h          = (const float*)d_in[0];
    const float* w1         = (const float*)d_in[1];
    const float* b1         = (const float*)d_in[2];
    const float* w2         = (const float*)d_in[3];
    const float* b2         = (const float*)d_in[4];
    const int*   word_start = (const int*)d_in[5];
    const int*   word_len   = (const int*)d_in[6];
    const int*   pair_idx   = (const int*)d_in[7];
    float*       out        = (float*)d_out;

    // workspace layout (all bf16)
    unsigned short* proj  = (unsigned short*)d_ws;                       // 10,485,760 B
    unsigned short* emb   = (unsigned short*)((char*)d_ws + 10485760);   // 12,582,912 B
    unsigned short* bmatT = (unsigned short*)((char*)d_ws + 23068672);   // 983,040 B
    unsigned short* zrow  = (unsigned short*)((char*)d_ws + 24051712);   // 1,280 B

    prep_kernel<<<dim3(1024), dim3(256), 0, stream>>>(
        h, w1, word_start, word_len, emb, bmatT, zrow);
    gemm_kernel<<<dim3(320), dim3(256), 0, stream>>>(emb, bmatT, proj);
    mlp_kernel <<<dim3(2048), dim3(256), 0, stream>>>(proj, zrow, b1, w2, b2, pair_idx, out);
}